// Round 4
// baseline (480.552 us; speedup 1.0000x reference)
//
#include <hip/hip_runtime.h>
#include <hip/hip_bf16.h>

#define T_TOK 4096
#define HD    1024
#define FFD   2048
#define NE    8
#define NTH_F 512

typedef __attribute__((ext_vector_type(8))) short short8;
typedef __attribute__((ext_vector_type(4))) float f32x4;

__device__ __forceinline__ unsigned short f2bf(float f) {
  __hip_bfloat16 h = __float2bfloat16(f);
  return __builtin_bit_cast(unsigned short, h);
}

__device__ __forceinline__ void gload_lds16(const unsigned short* g, unsigned short* l) {
  __builtin_amdgcn_global_load_lds(
      (const __attribute__((address_space(1))) unsigned int*)g,
      (__attribute__((address_space(3))) unsigned int*)l, 16, 0, 0);
}

// ---------------- gating + routing ----------------
__global__ __launch_bounds__(256) void gate_route_kernel(
    const float* __restrict__ x, const float* __restrict__ Wg,
    const float* __restrict__ bg,
    int* __restrict__ counts, int* __restrict__ ids, float* __restrict__ wts)
{
  int wave = threadIdx.x >> 6;
  int lane = threadIdx.x & 63;
  int t = blockIdx.x * 4 + wave;
  if (t >= T_TOK) return;

  float acc[NE];
#pragma unroll
  for (int e = 0; e < NE; ++e) acc[e] = 0.f;

  const float* xr = x + (size_t)t * HD;
  for (int h = lane; h < HD; h += 64) {
    float xv = xr[h];
    float4 a = *(const float4*)(Wg + (size_t)h * NE);
    float4 b = *(const float4*)(Wg + (size_t)h * NE + 4);
    acc[0] = fmaf(xv, a.x, acc[0]); acc[1] = fmaf(xv, a.y, acc[1]);
    acc[2] = fmaf(xv, a.z, acc[2]); acc[3] = fmaf(xv, a.w, acc[3]);
    acc[4] = fmaf(xv, b.x, acc[4]); acc[5] = fmaf(xv, b.y, acc[5]);
    acc[6] = fmaf(xv, b.z, acc[6]); acc[7] = fmaf(xv, b.w, acc[7]);
  }
#pragma unroll
  for (int off = 32; off > 0; off >>= 1) {
#pragma unroll
    for (int e = 0; e < NE; ++e) acc[e] += __shfl_xor(acc[e], off);
  }
  if (lane == 0) {
    float lg[NE];
#pragma unroll
    for (int e = 0; e < NE; ++e) lg[e] = acc[e] + bg[e];
    int i1 = 0;
#pragma unroll
    for (int e = 1; e < NE; ++e) if (lg[e] > lg[i1]) i1 = e;
    int i2 = (i1 == 0) ? 1 : 0;
#pragma unroll
    for (int e = 0; e < NE; ++e) if (e != i1 && lg[e] > lg[i2]) i2 = e;
    float p2 = expf(lg[i2] - lg[i1]);
    float s  = 1.f + p2;
    float w1 = 1.f / s;
    float w2 = p2 / s;
    int s1 = atomicAdd(&counts[i1], 1);
    ids[i1 * T_TOK + s1] = t; wts[i1 * T_TOK + s1] = w1;
    int s2 = atomicAdd(&counts[i2], 1);
    ids[i2 * T_TOK + s2] = t; wts[i2 * T_TOK + s2] = w2;
  }
}

// ---------------- prefix offsets (256-aligned) ----------------
__global__ void offs_kernel(const int* __restrict__ counts, int* __restrict__ offs) {
  if (threadIdx.x == 0) {
    int o = 0;
#pragma unroll
    for (int e = 0; e < NE; ++e) { offs[e] = o; o += (counts[e] + 255) & ~255; }
  }
}

// ---------------- weight transpose + bf16 convert ----------------
// in: [E][R][C] fp32 -> out: [E][C][R] bf16
__global__ __launch_bounds__(256) void transpose_cvt_kernel(
    const float* __restrict__ in, unsigned short* __restrict__ out,
    int R, int C)
{
  __shared__ float tile[64][69];
  const int z  = blockIdx.z;
  const int r0 = blockIdx.y * 64, c0 = blockIdx.x * 64;
  const int t  = threadIdx.x;
  const float* ip = in + ((size_t)z * R + r0) * C + c0;
  int tr = t >> 4, tc = (t & 15) * 4;
#pragma unroll
  for (int j = 0; j < 4; ++j) {
    float4 v = *(const float4*)(ip + (size_t)(tr + j * 16) * C + tc);
    float* tp = &tile[tr + j * 16][tc];
    tp[0] = v.x; tp[1] = v.y; tp[2] = v.z; tp[3] = v.w;
  }
  __syncthreads();
  unsigned short* op = out + ((size_t)z * C + c0) * R + r0;
  int oc = t >> 4, orr = (t & 15) * 4;
#pragma unroll
  for (int j = 0; j < 4; ++j) {
    int c = oc + j * 16;
    ushort4 w;
    w.x = f2bf(tile[orr + 0][c]);
    w.y = f2bf(tile[orr + 1][c]);
    w.z = f2bf(tile[orr + 2][c]);
    w.w = f2bf(tile[orr + 3][c]);
    *(ushort4*)(op + (size_t)c * R + orr) = w;
  }
}

// ---------------- gather x rows into expert-sorted bf16 array ----------------
// one block per 256-row tile; pads to 256-aligned count with zeros
__global__ __launch_bounds__(256) void gather_cvt_kernel(
    const float* __restrict__ x, const int* __restrict__ counts,
    const int* __restrict__ offs, const int* __restrict__ ids,
    unsigned short* __restrict__ Xg)
{
  const int e  = blockIdx.x & 7;
  const int rb = blockIdx.x >> 3;
  const int cnt = counts[e];
  const int padded = (cnt + 255) & ~255;
  if (rb * 256 >= padded) return;
  const int base = offs[e] + rb * 256;
  const int tid = threadIdx.x;
#pragma unroll 4
  for (int r = 0; r < 256; ++r) {
    int i = rb * 256 + r;
    unsigned short* orow = Xg + (size_t)(base + r) * HD + tid * 4;
    if (i < cnt) {
      const float* xr = x + (size_t)ids[e * T_TOK + i] * HD + tid * 4;
      float4 v = *(const float4*)xr;
      ushort4 u;
      u.x = f2bf(v.x); u.y = f2bf(v.y); u.z = f2bf(v.z); u.w = f2bf(v.w);
      *(ushort4*)orow = u;
    } else {
      *(ushort4*)orow = (ushort4){0, 0, 0, 0};
    }
  }
}

// ---------------- grouped pair-GEMM: 256-row tile, dbuf LDS, 1 barrier/K-step ----
// A: [pairRows][KD] bf16 (expert-sorted, 256-padded). BT: [E][ND][KD] bf16.
// Block: 512 thr = 8 waves (2M x 4N), wave tile 128 x (BN/4).
// G1M: Hout[p][col] = relu(A@B^T + bias)        (bias=b1, ND=FFD)
// else: out[tok][col] += wt * (A@B^T + bias)    (bias=b2, ND=HD)
template<int KD, int ND, int BN, bool G1M>
__global__ __launch_bounds__(512, 2) void pair_gemm256_kernel(
    const unsigned short* __restrict__ A,
    const unsigned short* __restrict__ BT,
    const float* __restrict__ bias,
    const int* __restrict__ counts, const int* __restrict__ offs,
    const int* __restrict__ ids, const float* __restrict__ wts,
    unsigned short* __restrict__ Hout, float* __restrict__ out)
{
  constexpr int WN = BN / 4;    // wave col span
  constexpr int NF = WN / 16;   // n-frags per wave
  constexpr int NT = KD / 64;   // K-steps

  const int bid = blockIdx.x;
  const int e   = bid & 7;      // XCD-pinned expert
  const int q   = bid >> 3;
  const int rt  = q & 15;       // row tile (fastest -> B panel hot in L2)
  const int ct  = q >> 4;       // col tile
  const int cnt = counts[e];
  if (rt * 256 >= cnt) return;
  const int row0 = offs[e] + rt * 256;

  __shared__ __align__(16) unsigned short As[2][256 * 64];
  __shared__ __align__(16) unsigned short Bs[2][BN * 64];

  const int tid  = threadIdx.x;
  const int w    = tid >> 6;
  const int lane = tid & 63;
  const int g    = lane >> 4;
  const int rA   = lane & 15;
  const int wr   = w >> 2;      // 0..1
  const int wc   = w & 3;       // 0..3

  const unsigned short* Abase = A + (size_t)row0 * KD;
  const unsigned short* Bbase = BT + ((size_t)e * ND + (size_t)ct * BN) * KD;
  const int srow   = lane >> 3;        // staging row within 8-row group
  const int schunk = (lane & 7) * 8;   // 16B chunk offset (elements)

  f32x4 acc[8][NF];
#pragma unroll
  for (int mf = 0; mf < 8; ++mf)
#pragma unroll
    for (int nf = 0; nf < NF; ++nf)
      acc[mf][nf] = (f32x4){0.f, 0.f, 0.f, 0.f};

  auto stage = [&](int buf, int kc) {
#pragma unroll
    for (int j = 0; j < 4; ++j) {
      const int rg = w * 32 + j * 8;
      gload_lds16(Abase + (size_t)(rg + srow) * KD + kc + schunk, &As[buf][rg * 64]);
    }
#pragma unroll
    for (int j = 0; j < BN / 64; ++j) {
      const int rg = w * (BN / 8) + j * 8;
      gload_lds16(Bbase + (size_t)(rg + srow) * KD + kc + schunk, &Bs[buf][rg * 64]);
    }
  };

  stage(0, 0);
  __syncthreads();   // implicit vmcnt(0) drain

  for (int t = 0; t < NT; ++t) {
    const int cur = t & 1;
    if (t + 1 < NT) stage(cur ^ 1, (t + 1) * 64);   // prefetch overlaps MFMA below
#pragma unroll
    for (int ks = 0; ks < 2; ++ks) {
      short8 bf[NF];
#pragma unroll
      for (int nf = 0; nf < NF; ++nf)
        bf[nf] = *(const short8*)&Bs[cur][(wc * WN + nf * 16 + rA) * 64 + ks * 32 + g * 8];
#pragma unroll
      for (int mf = 0; mf < 8; ++mf) {
        short8 af = *(const short8*)&As[cur][(wr * 128 + mf * 16 + rA) * 64 + ks * 32 + g * 8];
#pragma unroll
        for (int nf = 0; nf < NF; ++nf)
          acc[mf][nf] = __builtin_amdgcn_mfma_f32_16x16x32_bf16(af, bf[nf], acc[mf][nf], 0, 0, 0);
      }
    }
    __syncthreads();  // drains prefetch (vmcnt0) + fragment reads (lgkmcnt0)
  }

  // ---- epilogue ----
  float bv[NF];
#pragma unroll
  for (int nf = 0; nf < NF; ++nf)
    bv[nf] = bias[e * ND + ct * BN + wc * WN + nf * 16 + rA];

  if constexpr (G1M) {
#pragma unroll
    for (int mf = 0; mf < 8; ++mf)
#pragma unroll
      for (int r = 0; r < 4; ++r) {
        const int row = row0 + wr * 128 + mf * 16 + g * 4 + r;
        unsigned short* hrow = Hout + (size_t)row * FFD + ct * BN + wc * WN + rA;
#pragma unroll
        for (int nf = 0; nf < NF; ++nf)
          hrow[nf * 16] = f2bf(fmaxf(acc[mf][nf][r] + bv[nf], 0.f));
      }
  } else {
#pragma unroll
    for (int mf = 0; mf < 8; ++mf)
#pragma unroll
      for (int r = 0; r < 4; ++r) {
        const int i = rt * 256 + wr * 128 + mf * 16 + g * 4 + r;
        if (i >= cnt) continue;
        const int tok = ids[e * T_TOK + i];
        const float wt = wts[e * T_TOK + i];
        float* orow = out + (size_t)tok * HD + ct * BN + wc * WN + rA;
#pragma unroll
        for (int nf = 0; nf < NF; ++nf)
          atomicAdd(&orow[nf * 16], wt * (acc[mf][nf][r] + bv[nf]));
      }
  }
}

// ---------------- round-2 fused MFMA kernel (emergency fallback) ----------------
__global__ __launch_bounds__(NTH_F, 2) void moe_mlp_mfma_kernel(
    const float* __restrict__ x,
    const unsigned short* __restrict__ W1T,
    const unsigned short* __restrict__ W2T,
    const float* __restrict__ b1, const float* __restrict__ b2,
    const int* __restrict__ counts, const int* __restrict__ ids,
    const float* __restrict__ wts, float* __restrict__ out)
{
  const int bid  = blockIdx.x;
  const int e    = bid & 7;
  const int tile = bid >> 3;
  const int cnt  = counts[e];
  const int t0   = tile * 32;
  if (t0 >= cnt) return;

  __shared__ unsigned short xs[32 * HD];
  __shared__ unsigned short hs[32 * 512];
  __shared__ int   rows[32];
  __shared__ float tww[32];

  const int tid  = threadIdx.x;
  const int w    = tid >> 6;
  const int lane = tid & 63;
  const int g    = lane >> 4;
  const int rA   = lane & 15;

  if (tid < 32) {
    int idx = t0 + tid;
    rows[tid] = (idx < cnt) ? ids[e * T_TOK + idx] : -1;
    tww[tid]  = (idx < cnt) ? wts[e * T_TOK + idx] : 0.f;
  }
  __syncthreads();

#pragma unroll
  for (int it = 0; it < 8; ++it) {
    int c   = it * NTH_F + tid;
    int row = c >> 7;
    int ck  = c & 127;
    int sck = ck ^ (row & 7);
    short8 sv;
    int rsrc = rows[row];
    if (rsrc >= 0) {
      const float* xp = x + (size_t)rsrc * HD + ck * 8;
      float4 lo = *(const float4*)xp;
      float4 hi = *(const float4*)(xp + 4);
      sv[0] = (short)f2bf(lo.x); sv[1] = (short)f2bf(lo.y);
      sv[2] = (short)f2bf(lo.z); sv[3] = (short)f2bf(lo.w);
      sv[4] = (short)f2bf(hi.x); sv[5] = (short)f2bf(hi.y);
      sv[6] = (short)f2bf(hi.z); sv[7] = (short)f2bf(hi.w);
    } else {
      sv = (short8)0;
    }
    *(short8*)&xs[row * HD + (sck << 3)] = sv;
  }
  __syncthreads();

  f32x4 acc2[2][8];
#pragma unroll
  for (int mf = 0; mf < 2; ++mf)
#pragma unroll
    for (int nf = 0; nf < 8; ++nf)
      acc2[mf][nf] = (f32x4){0.f, 0.f, 0.f, 0.f};

  const unsigned short* W1e = W1T + (size_t)e * FFD * HD;
  const unsigned short* W2e = W2T + (size_t)e * HD * FFD;
  const int sw = rA & 7;

  for (int fc = 0; fc < FFD; fc += 512) {
    f32x4 acc1[2][4];
#pragma unroll
    for (int mf = 0; mf < 2; ++mf)
#pragma unroll
      for (int nf = 0; nf < 4; ++nf)
        acc1[mf][nf] = (f32x4){0.f, 0.f, 0.f, 0.f};

    const unsigned short* bbase = W1e + (size_t)(fc + w * 64 + rA) * HD + 8 * g;
    for (int k0 = 0; k0 < HD; k0 += 32) {
      int ckA = (k0 >> 3) + g;
      int sa  = ((ckA ^ sw) << 3);
      short8 a0 = *(const short8*)&xs[rA * HD + sa];
      short8 a1 = *(const short8*)&xs[(16 + rA) * HD + sa];
      short8 b0 = *(const short8*)(bbase + k0);
      short8 b1f = *(const short8*)(bbase + 16 * HD + k0);
      short8 b2f = *(const short8*)(bbase + 32 * HD + k0);
      short8 b3f = *(const short8*)(bbase + 48 * HD + k0);
      acc1[0][0] = __builtin_amdgcn_mfma_f32_16x16x32_bf16(a0, b0,  acc1[0][0], 0, 0, 0);
      acc1[1][0] = __builtin_amdgcn_mfma_f32_16x16x32_bf16(a1, b0,  acc1[1][0], 0, 0, 0);
      acc1[0][1] = __builtin_amdgcn_mfma_f32_16x16x32_bf16(a0, b1f, acc1[0][1], 0, 0, 0);
      acc1[1][1] = __builtin_amdgcn_mfma_f32_16x16x32_bf16(a1, b1f, acc1[1][1], 0, 0, 0);
      acc1[0][2] = __builtin_amdgcn_mfma_f32_16x16x32_bf16(a0, b2f, acc1[0][2], 0, 0, 0);
      acc1[1][2] = __builtin_amdgcn_mfma_f32_16x16x32_bf16(a1, b2f, acc1[1][2], 0, 0, 0);
      acc1[0][3] = __builtin_amdgcn_mfma_f32_16x16x32_bf16(a0, b3f, acc1[0][3], 0, 0, 0);
      acc1[1][3] = __builtin_amdgcn_mfma_f32_16x16x32_bf16(a1, b3f, acc1[1][3], 0, 0, 0);
    }

    __syncthreads();
    float b1v[4];
#pragma unroll
    for (int nf = 0; nf < 4; ++nf)
      b1v[nf] = b1[e * FFD + fc + w * 64 + nf * 16 + rA];
#pragma unroll
    for (int mf = 0; mf < 2; ++mf)
#pragma unroll
      for (int nf = 0; nf < 4; ++nf)
#pragma unroll
        for (int r = 0; r < 4; ++r) {
          int row = mf * 16 + g * 4 + r;
          int col = w * 64 + nf * 16 + rA;
          float hv = fmaxf(acc1[mf][nf][r] + b1v[nf], 0.f);
          int ck = col >> 3;
          hs[row * 512 + ((ck ^ (row & 7)) << 3) + (col & 7)] = f2bf(hv);
        }
    __syncthreads();

    const unsigned short* b2base = W2e + (size_t)(w * 128 + rA) * FFD + fc + 8 * g;
    for (int k0 = 0; k0 < 512; k0 += 32) {
      int ckA = (k0 >> 3) + g;
      int sa  = ((ckA ^ sw) << 3);
      short8 a0 = *(const short8*)&hs[rA * 512 + sa];
      short8 a1 = *(const short8*)&hs[(16 + rA) * 512 + sa];
#pragma unroll
      for (int nf = 0; nf < 8; ++nf) {
        short8 bv = *(const short8*)(b2base + (size_t)nf * 16 * FFD + k0);
        acc2[0][nf] = __builtin_amdgcn_mfma_f32_16x16x32_bf16(a0, bv, acc2[0][nf], 0, 0, 0);
        acc2[1][nf] = __builtin_amdgcn_mfma_f32_16x16x32_bf16(a1, bv, acc2[1][nf], 0, 0, 0);
      }
    }
  }

#pragma unroll
  for (int mf = 0; mf < 2; ++mf)
#pragma unroll
    for (int nf = 0; nf < 8; ++nf) {
      int col = w * 128 + nf * 16 + rA;
      float b2v = b2[e * HD + col];
#pragma unroll
      for (int r = 0; r < 4; ++r) {
        int row = mf * 16 + g * 4 + r;
        int tr = rows[row];
        if (tr < 0) continue;
        atomicAdd(&out[(size_t)tr * HD + col], tww[row] * (acc2[mf][nf][r] + b2v));
      }
    }
}

extern "C" void kernel_launch(void* const* d_in, const int* in_sizes, int n_in,
                              void* d_out, int out_size, void* d_ws, size_t ws_size,
                              hipStream_t stream) {
  const float* x  = (const float*)d_in[0];
  const float* Wg = (const float*)d_in[1];
  const float* bg = (const float*)d_in[2];
  const float* W1 = (const float*)d_in[3];
  const float* b1 = (const float*)d_in[4];
  const float* W2 = (const float*)d_in[5];
  const float* b2 = (const float*)d_in[6];
  float* out = (float*)d_out;

  // ws layout (main): [counts 512B][offs 512B][ids 128KB][wts 128KB]
  //                   [WT 32MB (W1T during G1, then W2T)][Xg 21MB][H 42MB]
  const size_t OFF_IDS = 1024;
  const size_t OFF_WTS = OFF_IDS + (size_t)T_TOK * NE * 4;
  const size_t OFF_WT  = OFF_WTS + (size_t)T_TOK * NE * 4;       // 263168
  const size_t OFF_XG  = OFF_WT + (size_t)NE * HD * FFD * 2;     // +32MB
  const size_t OFF_H   = OFF_XG + (size_t)10240 * HD * 2;        // +21MB
  const size_t REQ     = OFF_H + (size_t)10240 * FFD * 2;        // ~96.7MB
  const size_t REQ_FB  = OFF_XG + (size_t)NE * HD * FFD * 2;     // ~67.4MB

  int*   counts = (int*)d_ws;
  int*   offs   = (int*)((char*)d_ws + 512);
  int*   ids    = (int*)((char*)d_ws + OFF_IDS);
  float* wts    = (float*)((char*)d_ws + OFF_WTS);

  hipMemsetAsync(counts, 0, 1024, stream);
  hipMemsetAsync(d_out, 0, (size_t)out_size * sizeof(float), stream);

  gate_route_kernel<<<T_TOK / 4, 256, 0, stream>>>(x, Wg, bg, counts, ids, wts);

  if (ws_size >= REQ) {
    unsigned short* WT = (unsigned short*)((char*)d_ws + OFF_WT);
    unsigned short* Xg = (unsigned short*)((char*)d_ws + OFF_XG);
    unsigned short* H  = (unsigned short*)((char*)d_ws + OFF_H);

    offs_kernel<<<1, 64, 0, stream>>>(counts, offs);
    transpose_cvt_kernel<<<dim3(FFD / 64, HD / 64, NE), 256, 0, stream>>>(W1, WT, HD, FFD);
    gather_cvt_kernel<<<NE * 16, 256, 0, stream>>>(x, counts, offs, ids, Xg);

    pair_gemm256_kernel<HD, FFD, 256, true><<<NE * 16 * (FFD / 256), 512, 0, stream>>>(
        Xg, WT, b1, counts, offs, ids, wts, H, nullptr);

    // W1T dead now; reuse the buffer for W2T (stream-ordered, no extra ws)
    transpose_cvt_kernel<<<dim3(HD / 64, FFD / 64, NE), 256, 0, stream>>>(W2, WT, FFD, HD);

    pair_gemm256_kernel<FFD, HD, 128, false><<<NE * 16 * (HD / 128), 512, 0, stream>>>(
        H, WT, b2, counts, offs, ids, wts, nullptr, out);
  } else if (ws_size >= REQ_FB) {
    unsigned short* W1T = (unsigned short*)((char*)d_ws + OFF_WT);
    unsigned short* W2T = (unsigned short*)((char*)d_ws + OFF_XG);
    transpose_cvt_kernel<<<dim3(FFD / 64, HD / 64, NE), 256, 0, stream>>>(W1, W1T, HD, FFD);
    transpose_cvt_kernel<<<dim3(HD / 64, FFD / 64, NE), 256, 0, stream>>>(W2, W2T, FFD, HD);
    moe_mlp_mfma_kernel<<<(T_TOK / 32) * NE, NTH_F, 0, stream>>>(
        x, W1T, W2T, b1, b2, counts, ids, wts, out);
  }
}

// Round 5
// 422.077 us; speedup vs baseline: 1.1385x; 1.1385x over previous
//
#include <hip/hip_runtime.h>
#include <hip/hip_bf16.h>

#define T_TOK 4096
#define HD    1024
#define FFD   2048
#define NE    8
#define NTH_F 512

typedef __attribute__((ext_vector_type(8))) short short8;
typedef __attribute__((ext_vector_type(4))) float f32x4;

__device__ __forceinline__ unsigned short f2bf(float f) {
  __hip_bfloat16 h = __float2bfloat16(f);
  return __builtin_bit_cast(unsigned short, h);
}

__device__ __forceinline__ void gload_lds16(const unsigned short* g, unsigned short* l) {
  __builtin_amdgcn_global_load_lds(
      (const __attribute__((address_space(1))) unsigned int*)g,
      (__attribute__((address_space(3))) unsigned int*)l, 16, 0, 0);
}

// ---------------- gating + routing ----------------
__global__ __launch_bounds__(256) void gate_route_kernel(
    const float* __restrict__ x, const float* __restrict__ Wg,
    const float* __restrict__ bg,
    int* __restrict__ counts, int* __restrict__ ids, float* __restrict__ wts)
{
  int wave = threadIdx.x >> 6;
  int lane = threadIdx.x & 63;
  int t = blockIdx.x * 4 + wave;
  if (t >= T_TOK) return;

  float acc[NE];
#pragma unroll
  for (int e = 0; e < NE; ++e) acc[e] = 0.f;

  const float* xr = x + (size_t)t * HD;
  for (int h = lane; h < HD; h += 64) {
    float xv = xr[h];
    float4 a = *(const float4*)(Wg + (size_t)h * NE);
    float4 b = *(const float4*)(Wg + (size_t)h * NE + 4);
    acc[0] = fmaf(xv, a.x, acc[0]); acc[1] = fmaf(xv, a.y, acc[1]);
    acc[2] = fmaf(xv, a.z, acc[2]); acc[3] = fmaf(xv, a.w, acc[3]);
    acc[4] = fmaf(xv, b.x, acc[4]); acc[5] = fmaf(xv, b.y, acc[5]);
    acc[6] = fmaf(xv, b.z, acc[6]); acc[7] = fmaf(xv, b.w, acc[7]);
  }
#pragma unroll
  for (int off = 32; off > 0; off >>= 1) {
#pragma unroll
    for (int e = 0; e < NE; ++e) acc[e] += __shfl_xor(acc[e], off);
  }
  if (lane == 0) {
    float lg[NE];
#pragma unroll
    for (int e = 0; e < NE; ++e) lg[e] = acc[e] + bg[e];
    int i1 = 0;
#pragma unroll
    for (int e = 1; e < NE; ++e) if (lg[e] > lg[i1]) i1 = e;
    int i2 = (i1 == 0) ? 1 : 0;
#pragma unroll
    for (int e = 0; e < NE; ++e) if (e != i1 && lg[e] > lg[i2]) i2 = e;
    float p2 = expf(lg[i2] - lg[i1]);
    float s  = 1.f + p2;
    float w1 = 1.f / s;
    float w2 = p2 / s;
    int s1 = atomicAdd(&counts[i1], 1);
    ids[i1 * T_TOK + s1] = t; wts[i1 * T_TOK + s1] = w1;
    int s2 = atomicAdd(&counts[i2], 1);
    ids[i2 * T_TOK + s2] = t; wts[i2 * T_TOK + s2] = w2;
  }
}

// ---------------- prefix offsets (256-aligned) ----------------
__global__ void offs_kernel(const int* __restrict__ counts, int* __restrict__ offs) {
  if (threadIdx.x == 0) {
    int o = 0;
#pragma unroll
    for (int e = 0; e < NE; ++e) { offs[e] = o; o += (counts[e] + 255) & ~255; }
  }
}

// ---------------- weight transpose + bf16 convert ----------------
// in: [E][R][C] fp32 -> out: [E][C][R] bf16
__global__ __launch_bounds__(256) void transpose_cvt_kernel(
    const float* __restrict__ in, unsigned short* __restrict__ out,
    int R, int C)
{
  __shared__ float tile[64][69];
  const int z  = blockIdx.z;
  const int r0 = blockIdx.y * 64, c0 = blockIdx.x * 64;
  const int t  = threadIdx.x;
  const float* ip = in + ((size_t)z * R + r0) * C + c0;
  int tr = t >> 4, tc = (t & 15) * 4;
#pragma unroll
  for (int j = 0; j < 4; ++j) {
    float4 v = *(const float4*)(ip + (size_t)(tr + j * 16) * C + tc);
    float* tp = &tile[tr + j * 16][tc];
    tp[0] = v.x; tp[1] = v.y; tp[2] = v.z; tp[3] = v.w;
  }
  __syncthreads();
  unsigned short* op = out + ((size_t)z * C + c0) * R + r0;
  int oc = t >> 4, orr = (t & 15) * 4;
#pragma unroll
  for (int j = 0; j < 4; ++j) {
    int c = oc + j * 16;
    ushort4 w;
    w.x = f2bf(tile[orr + 0][c]);
    w.y = f2bf(tile[orr + 1][c]);
    w.z = f2bf(tile[orr + 2][c]);
    w.w = f2bf(tile[orr + 3][c]);
    *(ushort4*)(op + (size_t)c * R + orr) = w;
  }
}

// ---------------- gather x rows into expert-sorted bf16 array ----------------
__global__ __launch_bounds__(256) void gather_cvt_kernel(
    const float* __restrict__ x, const int* __restrict__ counts,
    const int* __restrict__ offs, const int* __restrict__ ids,
    unsigned short* __restrict__ Xg)
{
  const int e  = blockIdx.x & 7;
  const int rb = blockIdx.x >> 3;
  const int cnt = counts[e];
  const int padded = (cnt + 255) & ~255;
  if (rb * 256 >= padded) return;
  const int base = offs[e] + rb * 256;
  const int tid = threadIdx.x;
#pragma unroll 4
  for (int r = 0; r < 256; ++r) {
    int i = rb * 256 + r;
    unsigned short* orow = Xg + (size_t)(base + r) * HD + tid * 4;
    if (i < cnt) {
      const float* xr = x + (size_t)ids[e * T_TOK + i] * HD + tid * 4;
      float4 v = *(const float4*)xr;
      ushort4 u;
      u.x = f2bf(v.x); u.y = f2bf(v.y); u.z = f2bf(v.z); u.w = f2bf(v.w);
      *(ushort4*)orow = u;
    } else {
      *(ushort4*)orow = (ushort4){0, 0, 0, 0};
    }
  }
}

// ---------------- grouped pair-GEMM: 256-row tile, T2 swizzle + T4 counted vmcnt ----
// A: [pairRows][KD] bf16 (expert-sorted, 256-padded). BT: [E][ND][KD] bf16.
// Block: 512 thr = 8 waves (2M x 4N), wave tile 128 x (BN/4).
// LDS layout: row-major [row][64], 16B chunks XOR-swizzled by (row&7); staging
// achieves the swizzle by permuting the GLOBAL source chunk (gload_lds dest is
// linear in lane). ds_read applies the same XOR -> conflict-free.
template<int KD, int ND, int BN, bool G1M>
__global__ __launch_bounds__(512, 2) void pair_gemm256_kernel(
    const unsigned short* __restrict__ A,
    const unsigned short* __restrict__ BT,
    const float* __restrict__ bias,
    const int* __restrict__ counts, const int* __restrict__ offs,
    const int* __restrict__ ids, const float* __restrict__ wts,
    unsigned short* __restrict__ Hout, float* __restrict__ out)
{
  constexpr int WN    = BN / 4;      // wave col span
  constexpr int NF    = WN / 16;     // n-frags per wave
  constexpr int NT    = KD / 64;     // K-steps
  constexpr int LOADS = 4 + BN / 64; // gload_lds per thread per K-step

  const int bid = blockIdx.x;
  const int e   = bid & 7;      // XCD-pinned expert
  const int q   = bid >> 3;
  const int rt  = q & 15;       // row tile (fastest -> B panel hot in L2)
  const int ct  = q >> 4;       // col tile
  const int cnt = counts[e];
  if (rt * 256 >= cnt) return;
  const int row0 = offs[e] + rt * 256;

  __shared__ __align__(16) unsigned short As[2][256 * 64];
  __shared__ __align__(16) unsigned short Bs[2][BN * 64];

  const int tid  = threadIdx.x;
  const int w    = tid >> 6;
  const int lane = tid & 63;
  const int g    = lane >> 4;
  const int rA   = lane & 15;
  const int wr   = w >> 2;      // 0..1
  const int wc   = w & 3;       // 0..3
  const int sw   = rA & 7;      // read-side swizzle key

  const unsigned short* Abase = A + (size_t)row0 * KD;
  const unsigned short* Bbase = BT + ((size_t)e * ND + (size_t)ct * BN) * KD;
  const int srow = lane >> 3;                    // staging row within 8-row group
  const int lc8  = ((lane & 7) ^ srow) * 8;      // pre-swizzled source chunk

  f32x4 acc[8][NF];
#pragma unroll
  for (int mf = 0; mf < 8; ++mf)
#pragma unroll
    for (int nf = 0; nf < NF; ++nf)
      acc[mf][nf] = (f32x4){0.f, 0.f, 0.f, 0.f};

  auto stage = [&](int buf, int kc) {
#pragma unroll
    for (int j = 0; j < 4; ++j) {
      const int rg = w * 32 + j * 8;
      gload_lds16(Abase + (size_t)(rg + srow) * KD + kc + lc8, &As[buf][rg * 64]);
    }
#pragma unroll
    for (int j = 0; j < BN / 64; ++j) {
      const int rg = w * (BN / 8) + j * 8;
      gload_lds16(Bbase + (size_t)(rg + srow) * KD + kc + lc8, &Bs[buf][rg * 64]);
    }
  };

  stage(0, 0);

  for (int t = 0; t < NT; ++t) {
    const int cur = t & 1;
    if (t + 1 < NT) {
      stage(cur ^ 1, (t + 1) * 64);                       // prefetch next tile
      asm volatile("s_waitcnt vmcnt(%0)" :: "i"(LOADS) : "memory");  // only tile-t done
    } else {
      asm volatile("s_waitcnt vmcnt(0)" ::: "memory");
    }
    __builtin_amdgcn_sched_barrier(0);
    __builtin_amdgcn_s_barrier();          // tile-t visible to all waves
    __builtin_amdgcn_sched_barrier(0);

#pragma unroll
    for (int ks = 0; ks < 2; ++ks) {
      short8 bf[NF];
#pragma unroll
      for (int nf = 0; nf < NF; ++nf) {
        const int R = wc * WN + nf * 16 + rA;
        const int pc = (ks * 4 + g) ^ sw;
        bf[nf] = *(const short8*)&Bs[cur][R * 64 + pc * 8];
      }
      __builtin_amdgcn_s_setprio(1);
#pragma unroll
      for (int mf = 0; mf < 8; ++mf) {
        const int R = wr * 128 + mf * 16 + rA;
        const int pc = (ks * 4 + g) ^ sw;
        short8 af = *(const short8*)&As[cur][R * 64 + pc * 8];
#pragma unroll
        for (int nf = 0; nf < NF; ++nf)
          acc[mf][nf] = __builtin_amdgcn_mfma_f32_16x16x32_bf16(af, bf[nf], acc[mf][nf], 0, 0, 0);
      }
      __builtin_amdgcn_s_setprio(0);
    }

    asm volatile("s_waitcnt lgkmcnt(0)" ::: "memory");
    __builtin_amdgcn_sched_barrier(0);
    __builtin_amdgcn_s_barrier();          // all reads done; next DMA may overwrite
    __builtin_amdgcn_sched_barrier(0);
  }

  // ---- epilogue ----
  float bv[NF];
#pragma unroll
  for (int nf = 0; nf < NF; ++nf)
    bv[nf] = bias[e * ND + ct * BN + wc * WN + nf * 16 + rA];

  if constexpr (G1M) {
#pragma unroll
    for (int mf = 0; mf < 8; ++mf)
#pragma unroll
      for (int r = 0; r < 4; ++r) {
        const int row = row0 + wr * 128 + mf * 16 + g * 4 + r;
        unsigned short* hrow = Hout + (size_t)row * FFD + ct * BN + wc * WN + rA;
#pragma unroll
        for (int nf = 0; nf < NF; ++nf)
          hrow[nf * 16] = f2bf(fmaxf(acc[mf][nf][r] + bv[nf], 0.f));
      }
  } else {
#pragma unroll
    for (int mf = 0; mf < 8; ++mf)
#pragma unroll
      for (int r = 0; r < 4; ++r) {
        const int i = rt * 256 + wr * 128 + mf * 16 + g * 4 + r;
        if (i >= cnt) continue;
        const int tok = ids[e * T_TOK + i];
        const float wt = wts[e * T_TOK + i];
        float* orow = out + (size_t)tok * HD + ct * BN + wc * WN + rA;
#pragma unroll
        for (int nf = 0; nf < NF; ++nf)
          atomicAdd(&orow[nf * 16], wt * (acc[mf][nf][r] + bv[nf]));
      }
  }
}

// ---------------- round-2 fused MFMA kernel (emergency fallback) ----------------
__global__ __launch_bounds__(NTH_F, 2) void moe_mlp_mfma_kernel(
    const float* __restrict__ x,
    const unsigned short* __restrict__ W1T,
    const unsigned short* __restrict__ W2T,
    const float* __restrict__ b1, const float* __restrict__ b2,
    const int* __restrict__ counts, const int* __restrict__ ids,
    const float* __restrict__ wts, float* __restrict__ out)
{
  const int bid  = blockIdx.x;
  const int e    = bid & 7;
  const int tile = bid >> 3;
  const int cnt  = counts[e];
  const int t0   = tile * 32;
  if (t0 >= cnt) return;

  __shared__ unsigned short xs[32 * HD];
  __shared__ unsigned short hs[32 * 512];
  __shared__ int   rows[32];
  __shared__ float tww[32];

  const int tid  = threadIdx.x;
  const int w    = tid >> 6;
  const int lane = tid & 63;
  const int g    = lane >> 4;
  const int rA   = lane & 15;

  if (tid < 32) {
    int idx = t0 + tid;
    rows[tid] = (idx < cnt) ? ids[e * T_TOK + idx] : -1;
    tww[tid]  = (idx < cnt) ? wts[e * T_TOK + idx] : 0.f;
  }
  __syncthreads();

#pragma unroll
  for (int it = 0; it < 8; ++it) {
    int c   = it * NTH_F + tid;
    int row = c >> 7;
    int ck  = c & 127;
    int sck = ck ^ (row & 7);
    short8 sv;
    int rsrc = rows[row];
    if (rsrc >= 0) {
      const float* xp = x + (size_t)rsrc * HD + ck * 8;
      float4 lo = *(const float4*)xp;
      float4 hi = *(const float4*)(xp + 4);
      sv[0] = (short)f2bf(lo.x); sv[1] = (short)f2bf(lo.y);
      sv[2] = (short)f2bf(lo.z); sv[3] = (short)f2bf(lo.w);
      sv[4] = (short)f2bf(hi.x); sv[5] = (short)f2bf(hi.y);
      sv[6] = (short)f2bf(hi.z); sv[7] = (short)f2bf(hi.w);
    } else {
      sv = (short8)0;
    }
    *(short8*)&xs[row * HD + (sck << 3)] = sv;
  }
  __syncthreads();

  f32x4 acc2[2][8];
#pragma unroll
  for (int mf = 0; mf < 2; ++mf)
#pragma unroll
    for (int nf = 0; nf < 8; ++nf)
      acc2[mf][nf] = (f32x4){0.f, 0.f, 0.f, 0.f};

  const unsigned short* W1e = W1T + (size_t)e * FFD * HD;
  const unsigned short* W2e = W2T + (size_t)e * HD * FFD;
  const int sw = rA & 7;

  for (int fc = 0; fc < FFD; fc += 512) {
    f32x4 acc1[2][4];
#pragma unroll
    for (int mf = 0; mf < 2; ++mf)
#pragma unroll
      for (int nf = 0; nf < 4; ++nf)
        acc1[mf][nf] = (f32x4){0.f, 0.f, 0.f, 0.f};

    const unsigned short* bbase = W1e + (size_t)(fc + w * 64 + rA) * HD + 8 * g;
    for (int k0 = 0; k0 < HD; k0 += 32) {
      int ckA = (k0 >> 3) + g;
      int sa  = ((ckA ^ sw) << 3);
      short8 a0 = *(const short8*)&xs[rA * HD + sa];
      short8 a1 = *(const short8*)&xs[(16 + rA) * HD + sa];
      short8 b0 = *(const short8*)(bbase + k0);
      short8 b1f = *(const short8*)(bbase + 16 * HD + k0);
      short8 b2f = *(const short8*)(bbase + 32 * HD + k0);
      short8 b3f = *(const short8*)(bbase + 48 * HD + k0);
      acc1[0][0] = __builtin_amdgcn_mfma_f32_16x16x32_bf16(a0, b0,  acc1[0][0], 0, 0, 0);
      acc1[1][0] = __builtin_amdgcn_mfma_f32_16x16x32_bf16(a1, b0,  acc1[1][0], 0, 0, 0);
      acc1[0][1] = __builtin_amdgcn_mfma_f32_16x16x32_bf16(a0, b1f, acc1[0][1], 0, 0, 0);
      acc1[1][1] = __builtin_amdgcn_mfma_f32_16x16x32_bf16(a1, b1f, acc1[1][1], 0, 0, 0);
      acc1[0][2] = __builtin_amdgcn_mfma_f32_16x16x32_bf16(a0, b2f, acc1[0][2], 0, 0, 0);
      acc1[1][2] = __builtin_amdgcn_mfma_f32_16x16x32_bf16(a1, b2f, acc1[1][2], 0, 0, 0);
      acc1[0][3] = __builtin_amdgcn_mfma_f32_16x16x32_bf16(a0, b3f, acc1[0][3], 0, 0, 0);
      acc1[1][3] = __builtin_amdgcn_mfma_f32_16x16x32_bf16(a1, b3f, acc1[1][3], 0, 0, 0);
    }

    __syncthreads();
    float b1v[4];
#pragma unroll
    for (int nf = 0; nf < 4; ++nf)
      b1v[nf] = b1[e * FFD + fc + w * 64 + nf * 16 + rA];
#pragma unroll
    for (int mf = 0; mf < 2; ++mf)
#pragma unroll
      for (int nf = 0; nf < 4; ++nf)
#pragma unroll
        for (int r = 0; r < 4; ++r) {
          int row = mf * 16 + g * 4 + r;
          int col = w * 64 + nf * 16 + rA;
          float hv = fmaxf(acc1[mf][nf][r] + b1v[nf], 0.f);
          int ck = col >> 3;
          hs[row * 512 + ((ck ^ (row & 7)) << 3) + (col & 7)] = f2bf(hv);
        }
    __syncthreads();

    const unsigned short* b2base = W2e + (size_t)(w * 128 + rA) * FFD + fc + 8 * g;
    for (int k0 = 0; k0 < 512; k0 += 32) {
      int ckA = (k0 >> 3) + g;
      int sa  = ((ckA ^ sw) << 3);
      short8 a0 = *(const short8*)&hs[rA * 512 + sa];
      short8 a1 = *(const short8*)&hs[(16 + rA) * 512 + sa];
#pragma unroll
      for (int nf = 0; nf < 8; ++nf) {
        short8 bv = *(const short8*)(b2base + (size_t)nf * 16 * FFD + k0);
        acc2[0][nf] = __builtin_amdgcn_mfma_f32_16x16x32_bf16(a0, bv, acc2[0][nf], 0, 0, 0);
        acc2[1][nf] = __builtin_amdgcn_mfma_f32_16x16x32_bf16(a1, bv, acc2[1][nf], 0, 0, 0);
      }
    }
  }

#pragma unroll
  for (int mf = 0; mf < 2; ++mf)
#pragma unroll
    for (int nf = 0; nf < 8; ++nf) {
      int col = w * 128 + nf * 16 + rA;
      float b2v = b2[e * HD + col];
#pragma unroll
      for (int r = 0; r < 4; ++r) {
        int row = mf * 16 + g * 4 + r;
        int tr = rows[row];
        if (tr < 0) continue;
        atomicAdd(&out[(size_t)tr * HD + col], tww[row] * (acc2[mf][nf][r] + b2v));
      }
    }
}

extern "C" void kernel_launch(void* const* d_in, const int* in_sizes, int n_in,
                              void* d_out, int out_size, void* d_ws, size_t ws_size,
                              hipStream_t stream) {
  const float* x  = (const float*)d_in[0];
  const float* Wg = (const float*)d_in[1];
  const float* bg = (const float*)d_in[2];
  const float* W1 = (const float*)d_in[3];
  const float* b1 = (const float*)d_in[4];
  const float* W2 = (const float*)d_in[5];
  const float* b2 = (const float*)d_in[6];
  float* out = (float*)d_out;

  // ws layout (main): [counts 512B][offs 512B][ids 128KB][wts 128KB]
  //                   [WT 32MB (W1T during G1, then W2T)][Xg 21MB][H 42MB]
  const size_t OFF_IDS = 1024;
  const size_t OFF_WTS = OFF_IDS + (size_t)T_TOK * NE * 4;
  const size_t OFF_WT  = OFF_WTS + (size_t)T_TOK * NE * 4;       // 263168
  const size_t OFF_XG  = OFF_WT + (size_t)NE * HD * FFD * 2;     // +32MB
  const size_t OFF_H   = OFF_XG + (size_t)10240 * HD * 2;        // +21MB
  const size_t REQ     = OFF_H + (size_t)10240 * FFD * 2;        // ~96.7MB
  const size_t REQ_FB  = OFF_XG + (size_t)NE * HD * FFD * 2;     // ~67.4MB

  int*   counts = (int*)d_ws;
  int*   offs   = (int*)((char*)d_ws + 512);
  int*   ids    = (int*)((char*)d_ws + OFF_IDS);
  float* wts    = (float*)((char*)d_ws + OFF_WTS);

  hipMemsetAsync(counts, 0, 1024, stream);
  hipMemsetAsync(d_out, 0, (size_t)out_size * sizeof(float), stream);

  gate_route_kernel<<<T_TOK / 4, 256, 0, stream>>>(x, Wg, bg, counts, ids, wts);

  if (ws_size >= REQ) {
    unsigned short* WT = (unsigned short*)((char*)d_ws + OFF_WT);
    unsigned short* Xg = (unsigned short*)((char*)d_ws + OFF_XG);
    unsigned short* H  = (unsigned short*)((char*)d_ws + OFF_H);

    offs_kernel<<<1, 64, 0, stream>>>(counts, offs);
    transpose_cvt_kernel<<<dim3(FFD / 64, HD / 64, NE), 256, 0, stream>>>(W1, WT, HD, FFD);
    gather_cvt_kernel<<<NE * 16, 256, 0, stream>>>(x, counts, offs, ids, Xg);

    pair_gemm256_kernel<HD, FFD, 256, true><<<NE * 16 * (FFD / 256), 512, 0, stream>>>(
        Xg, WT, b1, counts, offs, ids, wts, H, nullptr);

    // W1T dead now; reuse the buffer for W2T (stream-ordered, no extra ws)
    transpose_cvt_kernel<<<dim3(HD / 64, FFD / 64, NE), 256, 0, stream>>>(W2, WT, FFD, HD);

    pair_gemm256_kernel<FFD, HD, 128, false><<<NE * 16 * (HD / 128), 512, 0, stream>>>(
        H, WT, b2, counts, offs, ids, wts, nullptr, out);
  } else if (ws_size >= REQ_FB) {
    unsigned short* W1T = (unsigned short*)((char*)d_ws + OFF_WT);
    unsigned short* W2T = (unsigned short*)((char*)d_ws + OFF_XG);
    transpose_cvt_kernel<<<dim3(FFD / 64, HD / 64, NE), 256, 0, stream>>>(W1, W1T, HD, FFD);
    transpose_cvt_kernel<<<dim3(HD / 64, FFD / 64, NE), 256, 0, stream>>>(W2, W2T, FFD, HD);
    moe_mlp_mfma_kernel<<<(T_TOK / 32) * NE, NTH_F, 0, stream>>>(
        x, W1T, W2T, b1, b2, counts, ids, wts, out);
  }
}

// Round 6
// 311.807 us; speedup vs baseline: 1.5412x; 1.3536x over previous
//
#include <hip/hip_runtime.h>
#include <hip/hip_bf16.h>

#define T_TOK 4096
#define HD    1024
#define FFD   2048
#define NE    8
#define TWMAX 71   // max 128-row tiles: 8192/128 + 7 partials

typedef __attribute__((ext_vector_type(8))) short short8;
typedef __attribute__((ext_vector_type(4))) float f32x4;

__device__ __forceinline__ unsigned short f2bf(float f) {
  __hip_bfloat16 h = __float2bfloat16(f);
  return __builtin_bit_cast(unsigned short, h);
}

__device__ __forceinline__ void gload_lds16(const unsigned short* g, unsigned short* l) {
  __builtin_amdgcn_global_load_lds(
      (const __attribute__((address_space(1))) unsigned int*)g,
      (__attribute__((address_space(3))) unsigned int*)l, 16, 0, 0);
}

// map global 128-row tile index j -> (expert e, tile-in-expert rt, packed row0)
__device__ __forceinline__ bool decode_tile(const int* __restrict__ counts,
                                            int j, int& e, int& rt, int& row0) {
  int acc = 0, base = 0;
#pragma unroll
  for (int k = 0; k < NE; ++k) {
    int nt = (counts[k] + 127) >> 7;
    if (j < acc + nt) { e = k; rt = j - acc; row0 = base + (rt << 7); return true; }
    acc += nt; base += nt << 7;
  }
  return false;
}

// ---------------- gating + routing (+ zero out) ----------------
__global__ __launch_bounds__(256) void gate_route_kernel(
    const float* __restrict__ x, const float* __restrict__ Wg,
    const float* __restrict__ bg,
    int* __restrict__ counts, int* __restrict__ ids, float* __restrict__ wts,
    float* __restrict__ out)
{
  // fold memset(out): 1024 blocks x 256 thr x 16 floats = 4096*1024
  {
    size_t b = ((size_t)blockIdx.x * 256 + threadIdx.x) * 16;
    float4 z = make_float4(0.f, 0.f, 0.f, 0.f);
#pragma unroll
    for (int q = 0; q < 4; ++q) *(float4*)(out + b + q * 4) = z;
  }

  int wave = threadIdx.x >> 6;
  int lane = threadIdx.x & 63;
  int t = blockIdx.x * 4 + wave;
  if (t >= T_TOK) return;

  float acc[NE];
#pragma unroll
  for (int e = 0; e < NE; ++e) acc[e] = 0.f;

  const float* xr = x + (size_t)t * HD;
  for (int h = lane; h < HD; h += 64) {
    float xv = xr[h];
    float4 a = *(const float4*)(Wg + (size_t)h * NE);
    float4 b = *(const float4*)(Wg + (size_t)h * NE + 4);
    acc[0] = fmaf(xv, a.x, acc[0]); acc[1] = fmaf(xv, a.y, acc[1]);
    acc[2] = fmaf(xv, a.z, acc[2]); acc[3] = fmaf(xv, a.w, acc[3]);
    acc[4] = fmaf(xv, b.x, acc[4]); acc[5] = fmaf(xv, b.y, acc[5]);
    acc[6] = fmaf(xv, b.z, acc[6]); acc[7] = fmaf(xv, b.w, acc[7]);
  }
#pragma unroll
  for (int off = 32; off > 0; off >>= 1) {
#pragma unroll
    for (int e = 0; e < NE; ++e) acc[e] += __shfl_xor(acc[e], off);
  }
  if (lane == 0) {
    float lg[NE];
#pragma unroll
    for (int e = 0; e < NE; ++e) lg[e] = acc[e] + bg[e];
    int i1 = 0;
#pragma unroll
    for (int e = 1; e < NE; ++e) if (lg[e] > lg[i1]) i1 = e;
    int i2 = (i1 == 0) ? 1 : 0;
#pragma unroll
    for (int e = 0; e < NE; ++e) if (e != i1 && lg[e] > lg[i2]) i2 = e;
    float p2 = expf(lg[i2] - lg[i1]);
    float s  = 1.f + p2;
    float w1 = 1.f / s;
    float w2 = p2 / s;
    int s1 = atomicAdd(&counts[i1], 1);
    ids[i1 * T_TOK + s1] = t; wts[i1 * T_TOK + s1] = w1;
    int s2 = atomicAdd(&counts[i2], 1);
    ids[i2 * T_TOK + s2] = t; wts[i2 * T_TOK + s2] = w2;
  }
}

// ---------------- weight transpose + bf16 convert ----------------
// in: [E][R][C] fp32 -> out: [E][C][R] bf16
__global__ __launch_bounds__(256) void transpose_cvt_kernel(
    const float* __restrict__ in, unsigned short* __restrict__ out,
    int R, int C)
{
  __shared__ float tile[64][69];
  const int z  = blockIdx.z;
  const int r0 = blockIdx.y * 64, c0 = blockIdx.x * 64;
  const int t  = threadIdx.x;
  const float* ip = in + ((size_t)z * R + r0) * C + c0;
  int tr = t >> 4, tc = (t & 15) * 4;
#pragma unroll
  for (int j = 0; j < 4; ++j) {
    float4 v = *(const float4*)(ip + (size_t)(tr + j * 16) * C + tc);
    float* tp = &tile[tr + j * 16][tc];
    tp[0] = v.x; tp[1] = v.y; tp[2] = v.z; tp[3] = v.w;
  }
  __syncthreads();
  unsigned short* op = out + ((size_t)z * C + c0) * R + r0;
  int oc = t >> 4, orr = (t & 15) * 4;
#pragma unroll
  for (int j = 0; j < 4; ++j) {
    int c = oc + j * 16;
    ushort4 w;
    w.x = f2bf(tile[orr + 0][c]);
    w.y = f2bf(tile[orr + 1][c]);
    w.z = f2bf(tile[orr + 2][c]);
    w.w = f2bf(tile[orr + 3][c]);
    *(ushort4*)(op + (size_t)c * R + orr) = w;
  }
}

// ---------------- gather x rows into expert-sorted bf16 array ----------------
// one block per 128-row tile (decode_tile); zero-pads tail rows
__global__ __launch_bounds__(256) void gather_cvt_kernel(
    const float* __restrict__ x, const int* __restrict__ counts,
    const int* __restrict__ ids, unsigned short* __restrict__ Xg)
{
  int e, rt, row0;
  if (!decode_tile(counts, blockIdx.x, e, rt, row0)) return;
  const int cnt = counts[e];
  const int tid = threadIdx.x;
#pragma unroll 4
  for (int r = 0; r < 128; ++r) {
    int i = rt * 128 + r;
    unsigned short* orow = Xg + (size_t)(row0 + r) * HD + tid * 4;
    if (i < cnt) {
      const float* xr = x + (size_t)ids[e * T_TOK + i] * HD + tid * 4;
      float4 v = *(const float4*)xr;
      ushort4 u;
      u.x = f2bf(v.x); u.y = f2bf(v.y); u.z = f2bf(v.z); u.w = f2bf(v.w);
      *(ushort4*)orow = u;
    } else {
      *(ushort4*)orow = (ushort4){0, 0, 0, 0};
    }
  }
}

// ---------------- grouped pair-GEMM: m97 structure (128^2, 4 waves, 3 blk/CU) ----
// A: [packedRows][KD] bf16 (expert-sorted, 128-padded). BT: [E][ND][KD] bf16.
// LDS single-buffered 32KB, 2 barriers/K-step; XOR-swizzled 16B chunks
// (source-permuted for global_load_lds; same XOR on ds_read) -> 0 conflicts.
// G1M: Hout[p][col] = relu(A@B^T + bias); else out[tok][col] += wt*(A@B^T+bias).
template<int KD, int ND, bool G1M>
__global__ __launch_bounds__(256, 3) void pair_gemm128_kernel(
    const unsigned short* __restrict__ A,
    const unsigned short* __restrict__ BT,
    const float* __restrict__ bias,
    const int* __restrict__ counts, const int* __restrict__ ids,
    const float* __restrict__ wts,
    unsigned short* __restrict__ Hout, float* __restrict__ out)
{
  int e, rt, row0;
  if (!decode_tile(counts, blockIdx.y, e, rt, row0)) return;
  const int ct  = blockIdx.x;
  const int cnt = counts[e];

  __shared__ __align__(16) unsigned short As[128 * 64];
  __shared__ __align__(16) unsigned short Bs[128 * 64];

  const int tid  = threadIdx.x;
  const int w    = tid >> 6;
  const int lane = tid & 63;
  const int g    = lane >> 4;     // k-group 0..3
  const int rA   = lane & 15;     // row/col within fragment
  const int wr   = w >> 1;        // wave quadrant row 0..1
  const int wc   = w & 1;         // wave quadrant col 0..1
  const int sw   = rA & 7;        // read-side swizzle key
  const int srow = lane >> 3;                 // staging row in 8-row group
  const int lc8  = ((lane & 7) ^ srow) * 8;   // pre-swizzled source chunk

  const unsigned short* Ab = A + (size_t)row0 * KD;
  const unsigned short* Bb = BT + ((size_t)e * ND + (size_t)ct * 128) * KD;

  f32x4 acc[4][4];
#pragma unroll
  for (int mf = 0; mf < 4; ++mf)
#pragma unroll
    for (int nf = 0; nf < 4; ++nf)
      acc[mf][nf] = (f32x4){0.f, 0.f, 0.f, 0.f};

  for (int kc = 0; kc < KD; kc += 64) {
    __syncthreads();   // all waves done reading As/Bs
#pragma unroll
    for (int jj = 0; jj < 4; ++jj) {
      const int rg = w * 32 + jj * 8;   // 4 waves x 4 instr x 8 rows = 128
      gload_lds16(Ab + (size_t)(rg + srow) * KD + kc + lc8, &As[rg * 64]);
      gload_lds16(Bb + (size_t)(rg + srow) * KD + kc + lc8, &Bs[rg * 64]);
    }
    __syncthreads();   // drains vmcnt(0) -> tile visible (m97 pattern, 3 blk/CU hide it)
#pragma unroll
    for (int ks = 0; ks < 2; ++ks) {
      const int pc = ((ks * 4 + g) ^ sw) << 3;
      short8 af[4], bf[4];
#pragma unroll
      for (int mf = 0; mf < 4; ++mf)
        af[mf] = *(const short8*)&As[(wr * 64 + mf * 16 + rA) * 64 + pc];
#pragma unroll
      for (int nf = 0; nf < 4; ++nf)
        bf[nf] = *(const short8*)&Bs[(wc * 64 + nf * 16 + rA) * 64 + pc];
#pragma unroll
      for (int mf = 0; mf < 4; ++mf)
#pragma unroll
        for (int nf = 0; nf < 4; ++nf)
          acc[mf][nf] = __builtin_amdgcn_mfma_f32_16x16x32_bf16(
              af[mf], bf[nf], acc[mf][nf], 0, 0, 0);
    }
  }

  // ---- epilogue ----
  float bv[4];
#pragma unroll
  for (int nf = 0; nf < 4; ++nf)
    bv[nf] = bias[e * ND + ct * 128 + wc * 64 + nf * 16 + rA];

  if constexpr (G1M) {
#pragma unroll
    for (int mf = 0; mf < 4; ++mf)
#pragma unroll
      for (int r = 0; r < 4; ++r) {
        const int row = row0 + wr * 64 + mf * 16 + g * 4 + r;
        unsigned short* hrow = Hout + (size_t)row * FFD + ct * 128 + wc * 64 + rA;
#pragma unroll
        for (int nf = 0; nf < 4; ++nf)
          hrow[nf * 16] = f2bf(fmaxf(acc[mf][nf][r] + bv[nf], 0.f));
      }
  } else {
#pragma unroll
    for (int mf = 0; mf < 4; ++mf)
#pragma unroll
      for (int r = 0; r < 4; ++r) {
        const int i = rt * 128 + wr * 64 + mf * 16 + g * 4 + r;
        if (i >= cnt) continue;
        const int tok = ids[e * T_TOK + i];
        const float wt = wts[e * T_TOK + i];
        float* orow = out + (size_t)tok * HD + ct * 128 + wc * 64 + rA;
#pragma unroll
        for (int nf = 0; nf < 4; ++nf)
          atomicAdd(&orow[nf * 16], wt * (acc[mf][nf][r] + bv[nf]));
      }
  }
}

extern "C" void kernel_launch(void* const* d_in, const int* in_sizes, int n_in,
                              void* d_out, int out_size, void* d_ws, size_t ws_size,
                              hipStream_t stream) {
  const float* x  = (const float*)d_in[0];
  const float* Wg = (const float*)d_in[1];
  const float* bg = (const float*)d_in[2];
  const float* W1 = (const float*)d_in[3];
  const float* b1 = (const float*)d_in[4];
  const float* W2 = (const float*)d_in[5];
  const float* b2 = (const float*)d_in[6];
  float* out = (float*)d_out;

  // ws: [counts 2KB][ids 128KB][wts 128KB][WT 32MB (W1T then W2T)][Xg 18.9MB][H 37.8MB]
  const size_t OFF_IDS = 2048;
  const size_t OFF_WTS = OFF_IDS + (size_t)T_TOK * NE * 4;
  const size_t OFF_WT  = OFF_WTS + (size_t)T_TOK * NE * 4;
  const size_t OFF_XG  = OFF_WT + (size_t)NE * HD * FFD * 2;
  const size_t OFF_H   = OFF_XG + (size_t)9216 * HD * 2;
  const size_t REQ     = OFF_H + (size_t)9216 * FFD * 2;   // ~89 MB (< proven 96.7)

  int*   counts = (int*)d_ws;
  int*   ids    = (int*)((char*)d_ws + OFF_IDS);
  float* wts    = (float*)((char*)d_ws + OFF_WTS);

  hipMemsetAsync(counts, 0, 512, stream);

  gate_route_kernel<<<T_TOK / 4, 256, 0, stream>>>(x, Wg, bg, counts, ids, wts, out);

  if (ws_size >= REQ) {
    unsigned short* WT = (unsigned short*)((char*)d_ws + OFF_WT);
    unsigned short* Xg = (unsigned short*)((char*)d_ws + OFF_XG);
    unsigned short* H  = (unsigned short*)((char*)d_ws + OFF_H);

    transpose_cvt_kernel<<<dim3(FFD / 64, HD / 64, NE), 256, 0, stream>>>(W1, WT, HD, FFD);
    gather_cvt_kernel<<<TWMAX, 256, 0, stream>>>(x, counts, ids, Xg);

    pair_gemm128_kernel<HD, FFD, true><<<dim3(FFD / 128, TWMAX), 256, 0, stream>>>(
        Xg, WT, b1, counts, ids, wts, H, nullptr);

    // W1T dead; reuse buffer for W2T
    transpose_cvt_kernel<<<dim3(HD / 64, FFD / 64, NE), 256, 0, stream>>>(W2, WT, FFD, HD);

    pair_gemm128_kernel<FFD, HD, false><<<dim3(HD / 128, TWMAX), 256, 0, stream>>>(
        H, WT, b2, counts, ids, wts, nullptr, out);
  }
}

// Round 7
// 190.509 us; speedup vs baseline: 2.5225x; 1.6367x over previous
//
#include <hip/hip_runtime.h>
#include <hip/hip_bf16.h>

#define T_TOK 4096
#define HD    1024
#define FFD   2048
#define NE    8
#define TWMAX 71   // max 128-row tiles across experts

typedef __attribute__((ext_vector_type(8))) short short8;
typedef __attribute__((ext_vector_type(4))) float f32x4;

__device__ __forceinline__ unsigned short f2bf(float f) {
  __hip_bfloat16 h = __float2bfloat16(f);
  return __builtin_bit_cast(unsigned short, h);
}

__device__ __forceinline__ void gload_lds16(const unsigned short* g, unsigned short* l) {
  __builtin_amdgcn_global_load_lds(
      (const __attribute__((address_space(1))) unsigned int*)g,
      (__attribute__((address_space(3))) unsigned int*)l, 16, 0, 0);
}

// map global 128-row tile index j -> (expert e, tile-in-expert rt, packed row0)
__device__ __forceinline__ bool decode_tile(const int* __restrict__ counts,
                                            int j, int& e, int& rt, int& row0) {
  int acc = 0, base = 0;
#pragma unroll
  for (int k = 0; k < NE; ++k) {
    int nt = (counts[k] + 127) >> 7;
    if (j < acc + nt) { e = k; rt = j - acc; row0 = base + (rt << 7); return true; }
    acc += nt; base += nt << 7;
  }
  return false;
}

// ---------------- gate: logits -> top2 (no atomics), x->bf16, zero out ----------------
__global__ __launch_bounds__(256) void gate_kernel(
    const float* __restrict__ x, const float* __restrict__ Wg,
    const float* __restrict__ bg,
    int* __restrict__ top_i, float2* __restrict__ top_w,
    unsigned short* __restrict__ xbf, float* __restrict__ out)
{
  // fold memset(out): 1024 blocks x 256 thr x 16 floats
  {
    size_t b = ((size_t)blockIdx.x * 256 + threadIdx.x) * 16;
    float4 z = make_float4(0.f, 0.f, 0.f, 0.f);
#pragma unroll
    for (int q = 0; q < 4; ++q) *(float4*)(out + b + q * 4) = z;
  }

  const int wave = threadIdx.x >> 6;
  const int lane = threadIdx.x & 63;
  const int t = blockIdx.x * 4 + wave;
  if (t >= T_TOK) return;

  float acc[NE];
#pragma unroll
  for (int e = 0; e < NE; ++e) acc[e] = 0.f;

  const float* xr = x + (size_t)t * HD;
  unsigned short* xo = xbf + (size_t)t * HD;
#pragma unroll
  for (int it = 0; it < 4; ++it) {
    const int h0 = lane * 4 + it * 256;
    float4 xv = *(const float4*)(xr + h0);
#pragma unroll
    for (int j = 0; j < 4; ++j) {
      float xs = (&xv.x)[j];
      float4 a = *(const float4*)(Wg + (size_t)(h0 + j) * NE);
      float4 b = *(const float4*)(Wg + (size_t)(h0 + j) * NE + 4);
      acc[0] = fmaf(xs, a.x, acc[0]); acc[1] = fmaf(xs, a.y, acc[1]);
      acc[2] = fmaf(xs, a.z, acc[2]); acc[3] = fmaf(xs, a.w, acc[3]);
      acc[4] = fmaf(xs, b.x, acc[4]); acc[5] = fmaf(xs, b.y, acc[5]);
      acc[6] = fmaf(xs, b.z, acc[6]); acc[7] = fmaf(xs, b.w, acc[7]);
    }
    // write bf16 copy of the row chunk we already hold
    ushort4 u;
    u.x = f2bf(xv.x); u.y = f2bf(xv.y); u.z = f2bf(xv.z); u.w = f2bf(xv.w);
    *(ushort4*)(xo + h0) = u;
  }
#pragma unroll
  for (int off = 32; off > 0; off >>= 1) {
#pragma unroll
    for (int e = 0; e < NE; ++e) acc[e] += __shfl_xor(acc[e], off);
  }
  if (lane == 0) {
    float lg[NE];
#pragma unroll
    for (int e = 0; e < NE; ++e) lg[e] = acc[e] + bg[e];
    int i1 = 0;
#pragma unroll
    for (int e = 1; e < NE; ++e) if (lg[e] > lg[i1]) i1 = e;
    int i2 = (i1 == 0) ? 1 : 0;
#pragma unroll
    for (int e = 0; e < NE; ++e) if (e != i1 && lg[e] > lg[i2]) i2 = e;
    float p2 = expf(lg[i2] - lg[i1]);
    float s  = 1.f + p2;
    top_i[t] = i1 | (i2 << 8);
    top_w[t] = make_float2(1.f / s, p2 / s);
  }
}

// ---------------- route: per-expert compaction via prefix scan (deterministic) ----
__global__ __launch_bounds__(256) void route_kernel(
    const int* __restrict__ top_i, const float2* __restrict__ top_w,
    int* __restrict__ counts, int* __restrict__ ids, float* __restrict__ wts)
{
  const int e   = blockIdx.x;
  const int tid = threadIdx.x;
  __shared__ int psum[256];

  const int t0 = tid * 16;
  unsigned int flags = 0;
  int cnt = 0;
#pragma unroll
  for (int j = 0; j < 16; ++j) {
    int ti = top_i[t0 + j];
    bool m = ((ti & 255) == e) || (((ti >> 8) & 255) == e);
    flags |= (m ? 1u : 0u) << j;
    cnt += m;
  }
  psum[tid] = cnt;
  __syncthreads();
  for (int off = 1; off < 256; off <<= 1) {
    int v = (tid >= off) ? psum[tid - off] : 0;
    __syncthreads();
    psum[tid] += v;
    __syncthreads();
  }
  int rank = psum[tid] - cnt;  // exclusive prefix
#pragma unroll
  for (int j = 0; j < 16; ++j) {
    if (flags & (1u << j)) {
      int t = t0 + j;
      int ti = top_i[t];
      float2 w = top_w[t];
      ids[e * T_TOK + rank] = t;
      wts[e * T_TOK + rank] = ((ti & 255) == e) ? w.x : w.y;
      ++rank;
    }
  }
  if (tid == 255) counts[e] = psum[255];
}

// ---------------- weight transpose + bf16 convert ----------------
// in: [E][R][C] fp32 -> out: [E][C][R] bf16
__global__ __launch_bounds__(256) void transpose_cvt_kernel(
    const float* __restrict__ in, unsigned short* __restrict__ out,
    int R, int C)
{
  __shared__ float tile[64][69];
  const int z  = blockIdx.z;
  const int r0 = blockIdx.y * 64, c0 = blockIdx.x * 64;
  const int t  = threadIdx.x;
  const float* ip = in + ((size_t)z * R + r0) * C + c0;
  int tr = t >> 4, tc = (t & 15) * 4;
#pragma unroll
  for (int j = 0; j < 4; ++j) {
    float4 v = *(const float4*)(ip + (size_t)(tr + j * 16) * C + tc);
    float* tp = &tile[tr + j * 16][tc];
    tp[0] = v.x; tp[1] = v.y; tp[2] = v.z; tp[3] = v.w;
  }
  __syncthreads();
  unsigned short* op = out + ((size_t)z * C + c0) * R + r0;
  int oc = t >> 4, orr = (t & 15) * 4;
#pragma unroll
  for (int j = 0; j < 4; ++j) {
    int c = oc + j * 16;
    ushort4 w;
    w.x = f2bf(tile[orr + 0][c]);
    w.y = f2bf(tile[orr + 1][c]);
    w.z = f2bf(tile[orr + 2][c]);
    w.w = f2bf(tile[orr + 3][c]);
    *(ushort4*)(op + (size_t)c * R + orr) = w;
  }
}

// ---------------- grouped pair-GEMM: m97 structure (128^2, 4 waves, 3 blk/CU) ----
// GATHER_A: A-rows fetched via ids indirection from xbf (per-lane global src).
// else: A packed rows (H). BT: [E][ND][KD] bf16.
// XOR-swizzled 16B chunks (source-permuted for global_load_lds; same XOR on
// ds_read) -> 0 bank conflicts (verified round 5).
// G1M: Hout = relu(A@B^T + b1); else out[tok] += wt*(A@B^T + b2) (atomic).
template<int KD, int ND, bool G1M, bool GATHER_A>
__global__ __launch_bounds__(256, 3) void pair_gemm128_kernel(
    const unsigned short* __restrict__ A,
    const unsigned short* __restrict__ BT,
    const float* __restrict__ bias,
    const int* __restrict__ counts, const int* __restrict__ ids,
    const float* __restrict__ wts,
    unsigned short* __restrict__ Hout, float* __restrict__ out)
{
  int e, rt, row0;
  if (!decode_tile(counts, blockIdx.y, e, rt, row0)) return;
  const int ct  = blockIdx.x;
  const int cnt = counts[e];

  __shared__ __align__(16) unsigned short As[128 * 64];
  __shared__ __align__(16) unsigned short Bs[128 * 64];

  const int tid  = threadIdx.x;
  const int w    = tid >> 6;
  const int lane = tid & 63;
  const int g    = lane >> 4;     // k-group 0..3
  const int rA   = lane & 15;     // row/col within fragment
  const int wr   = w >> 1;        // wave quadrant row 0..1
  const int wc   = w & 1;         // wave quadrant col 0..1
  const int sw   = rA & 7;        // read-side swizzle key
  const int srow = lane >> 3;                 // staging row in 8-row group
  const int lc8  = ((lane & 7) ^ srow) * 8;   // pre-swizzled source chunk

  // per-thread A-row source pointers (ids indirection for G1)
  const unsigned short* arow[4];
#pragma unroll
  for (int jj = 0; jj < 4; ++jj) {
    const int lrow = w * 32 + jj * 8 + srow;
    int src;
    if constexpr (GATHER_A) {
      int i = rt * 128 + lrow;
      src = ids[e * T_TOK + (i < cnt ? i : cnt - 1)];
    } else {
      src = row0 + lrow;
    }
    arow[jj] = A + (size_t)src * KD + lc8;
  }
  const unsigned short* Bb = BT + ((size_t)e * ND + (size_t)ct * 128) * KD + lc8;

  f32x4 acc[4][4];
#pragma unroll
  for (int mf = 0; mf < 4; ++mf)
#pragma unroll
    for (int nf = 0; nf < 4; ++nf)
      acc[mf][nf] = (f32x4){0.f, 0.f, 0.f, 0.f};

  for (int kc = 0; kc < KD; kc += 64) {
    __syncthreads();   // all waves done reading As/Bs
#pragma unroll
    for (int jj = 0; jj < 4; ++jj) {
      const int rg = w * 32 + jj * 8;
      gload_lds16(arow[jj] + kc, &As[rg * 64]);
      gload_lds16(Bb + (size_t)(rg + srow) * KD + kc, &Bs[rg * 64]);
    }
    __syncthreads();   // drain; 3 blk/CU hide it (m97 pattern)
#pragma unroll
    for (int ks = 0; ks < 2; ++ks) {
      const int pc = ((ks * 4 + g) ^ sw) << 3;
      short8 af[4], bf[4];
#pragma unroll
      for (int mf = 0; mf < 4; ++mf)
        af[mf] = *(const short8*)&As[(wr * 64 + mf * 16 + rA) * 64 + pc];
#pragma unroll
      for (int nf = 0; nf < 4; ++nf)
        bf[nf] = *(const short8*)&Bs[(wc * 64 + nf * 16 + rA) * 64 + pc];
#pragma unroll
      for (int mf = 0; mf < 4; ++mf)
#pragma unroll
        for (int nf = 0; nf < 4; ++nf)
          acc[mf][nf] = __builtin_amdgcn_mfma_f32_16x16x32_bf16(
              af[mf], bf[nf], acc[mf][nf], 0, 0, 0);
    }
  }

  // ---- epilogue ----
  float bv[4];
#pragma unroll
  for (int nf = 0; nf < 4; ++nf)
    bv[nf] = bias[e * ND + ct * 128 + wc * 64 + nf * 16 + rA];

  if constexpr (G1M) {
#pragma unroll
    for (int mf = 0; mf < 4; ++mf)
#pragma unroll
      for (int r = 0; r < 4; ++r) {
        const int row = row0 + wr * 64 + mf * 16 + g * 4 + r;
        unsigned short* hrow = Hout + (size_t)row * FFD + ct * 128 + wc * 64 + rA;
#pragma unroll
        for (int nf = 0; nf < 4; ++nf)
          hrow[nf * 16] = f2bf(fmaxf(acc[mf][nf][r] + bv[nf], 0.f));
      }
  } else {
#pragma unroll
    for (int mf = 0; mf < 4; ++mf)
#pragma unroll
      for (int r = 0; r < 4; ++r) {
        const int i = rt * 128 + wr * 64 + mf * 16 + g * 4 + r;
        if (i >= cnt) continue;
        const int tok = ids[e * T_TOK + i];
        const float wt = wts[e * T_TOK + i];
        float* orow = out + (size_t)tok * HD + ct * 128 + wc * 64 + rA;
#pragma unroll
        for (int nf = 0; nf < 4; ++nf)
          atomicAdd(&orow[nf * 16], wt * (acc[mf][nf][r] + bv[nf]));
      }
  }
}

extern "C" void kernel_launch(void* const* d_in, const int* in_sizes, int n_in,
                              void* d_out, int out_size, void* d_ws, size_t ws_size,
                              hipStream_t stream) {
  const float* x  = (const float*)d_in[0];
  const float* Wg = (const float*)d_in[1];
  const float* bg = (const float*)d_in[2];
  const float* W1 = (const float*)d_in[3];
  const float* b1 = (const float*)d_in[4];
  const float* W2 = (const float*)d_in[5];
  const float* b2 = (const float*)d_in[6];
  float* out = (float*)d_out;

  // ws: [counts 512B][top_i 16K][top_w 32K][ids 128K][wts 128K]
  //     [xbf 8MB][WT 32MB (W1T then W2T)][H 37.75MB]  ~= 76.3 MB
  const size_t OFF_TOPI = 512;
  const size_t OFF_TOPW = OFF_TOPI + (size_t)T_TOK * 4;
  const size_t OFF_IDS  = OFF_TOPW + (size_t)T_TOK * 8;
  const size_t OFF_WTS  = OFF_IDS + (size_t)T_TOK * NE * 4;
  const size_t OFF_XBF  = OFF_WTS + (size_t)T_TOK * NE * 4;
  const size_t OFF_WT   = OFF_XBF + (size_t)T_TOK * HD * 2;
  const size_t OFF_H    = OFF_WT + (size_t)NE * HD * FFD * 2;
  const size_t REQ      = OFF_H + (size_t)9216 * FFD * 2;

  if (ws_size < REQ) return;

  int*            counts = (int*)d_ws;
  int*            top_i  = (int*)((char*)d_ws + OFF_TOPI);
  float2*         top_w  = (float2*)((char*)d_ws + OFF_TOPW);
  int*            ids    = (int*)((char*)d_ws + OFF_IDS);
  float*          wts    = (float*)((char*)d_ws + OFF_WTS);
  unsigned short* xbf    = (unsigned short*)((char*)d_ws + OFF_XBF);
  unsigned short* WT     = (unsigned short*)((char*)d_ws + OFF_WT);
  unsigned short* H      = (unsigned short*)((char*)d_ws + OFF_H);

  gate_kernel<<<T_TOK / 4, 256, 0, stream>>>(x, Wg, bg, top_i, top_w, xbf, out);
  route_kernel<<<NE, 256, 0, stream>>>(top_i, top_w, counts, ids, wts);

  transpose_cvt_kernel<<<dim3(FFD / 64, HD / 64, NE), 256, 0, stream>>>(W1, WT, HD, FFD);
  pair_gemm128_kernel<HD, FFD, true, true><<<dim3(FFD / 128, TWMAX), 256, 0, stream>>>(
      xbf, WT, b1, counts, ids, wts, H, nullptr);

  // W1T dead; reuse buffer for W2T
  transpose_cvt_kernel<<<dim3(HD / 64, FFD / 64, NE), 256, 0, stream>>>(W2, WT, FFD, HD);
  pair_gemm128_kernel<FFD, HD, false, false><<<dim3(HD / 128, TWMAX), 256, 0, stream>>>(
      H, WT, b2, counts, ids, wts, nullptr, out);
}